// Round 5
// baseline (120.150 us; speedup 1.0000x reference)
//
#include <hip/hip_runtime.h>

#define HSZ 256
#define WSZ 256
#define NFC 64
#define PLANE (HSZ * WSZ)

typedef __attribute__((ext_vector_type(8))) short short8;
typedef __attribute__((ext_vector_type(4))) float f32x4;

__device__ inline unsigned short f2bf(float f) {
    unsigned u = __builtin_bit_cast(unsigned, f);
    return (unsigned short)((u + 0x7fffu + ((u >> 16) & 1u)) >> 16);   // RTNE
}

// ============================================================================
// Fused dynamic-filter kernel, v6: 32(x) x 8(y) px tile, 512 threads (8 waves),
// grid (8,32,B) = 512 blocks -> 2 blocks/CU = 16 waves/CU (same as v5).
//
// v6 vs v5: byte + granularity attack.
//  - Bigger tile: h halo 1.875x -> 1.56x, i_t halo 1.40x -> 1.33x (~119 MB).
//  - Apply reads h DIRECT from global, fully vectorized: 9 float4/ch-iter
//    (left/mid/right f4 per row), zero scalars, zero LDS round-trip, zero
//    apply barriers. Iter-0 loads prefetched before the lf barrier.
//  - Out-writes are full 128B lines per wave (8 contiguous float4).
//  - Chunked XCD swizzle: contiguous 8-tile-row chunks per XCD (halo + line
//    sharing inside one L2), not interleaved.
//
// LDS 41856 B (2/CU by grid; 3 would fit):
//   [0,     32640) : xs  - i_t tile, 340 sp (10y x 34x) x 48 shorts
//   [32640, 40416) : lwT - conv_w transposed [oc][k=kk*48+ic] bf16, stride 432
//   [32640, 41856) : lf  - filters [9][8][32] f32 (overlays lwT after B2)
// Barriers: B1 (xs+lwT ready), B2 (lwT reads done), B3 (lf ready). Total 3.
// ============================================================================
__global__ __launch_bounds__(512, 4) void fused_dynfilter_v6(
    const float* __restrict__ hbuf,
    const float* __restrict__ i_t,
    const float* __restrict__ wbuf,
    const float* __restrict__ bias,
    float* __restrict__ out)
{
    __shared__ __align__(16) unsigned char smem[41856];
    unsigned short* const xs  = (unsigned short*)smem;            // 340 x 48
    unsigned short* const lwT = (unsigned short*)(smem + 32640);  // 9 x 432
    float* const lf = (float*)(smem + 32640);                     // 9 x 8 x 32

    const int tid = threadIdx.x;

    // chunked XCD swizzle: XCD x owns contiguous nid range [x*q, (x+1)*q)
    const int lin = blockIdx.x + 8 * (blockIdx.y + 32 * blockIdx.z);
    const int q   = ((int)gridDim.z * 256) >> 3;                  // 32*B
    const int nid = (lin & 7) * q + (lin >> 3);
    const int b   = nid >> 8;
    const int rem = nid & 255;
    const int X0  = (rem & 7) * 32;
    const int Y0  = (rem >> 3) * 8;

    const int lane = tid & 63;
    const int l15  = lane & 15;     // A: px col (within 16-col half) / B,C: oc
    const int kg   = lane >> 4;     // k-subgroup
    const int wv   = tid >> 6;      // wave: xh = wv&1, rows 2*(wv>>1)+{0,1}
    const int xh   = wv & 1;
    const int r0   = (wv >> 1) * 2;

    const float bv = (l15 < 9) ? bias[l15] : 0.f;
    const float* itb = i_t + (size_t)b * 3 * (PLANE * 16);

    // ---- phase 0a: stage shuffled i_t tile (4080 float4 jobs, 8 rounds)
    {
        float4 lreg[8]; int sdst[8];
#pragma unroll
        for (int k = 0; k < 8; ++k) {
            const int v = tid + 512 * k;
            const int sp = v / 12, t = v - sp * 12;          // t = c3*4+fy
            const int c3 = t >> 2, fy = t & 3;
            const int ly = sp / 34, lx = sp - ly * 34;
            const int Y = Y0 - 1 + ly, X = X0 - 1 + lx;
            float4 val = make_float4(0.f, 0.f, 0.f, 0.f);
            if (v < 4080 && (unsigned)Y < HSZ && (unsigned)X < WSZ)
                val = *(const float4*)(itb + ((size_t)c3 * 1024 + (4 * Y + fy)) * 1024 + 4 * X);
            lreg[k] = val;
            sdst[k] = (v < 4080) ? (sp * 48 + t * 4) : -1;
        }
#pragma unroll
        for (int k = 0; k < 8; ++k)
            if (sdst[k] >= 0) {
                ushort4 u{f2bf(lreg[k].x), f2bf(lreg[k].y), f2bf(lreg[k].z), f2bf(lreg[k].w)};
                *(ushort4*)(xs + sdst[k]) = u;
            }
    }

    // ---- phase 0b: stage conv_w -> lwT[oc*432 + kk*48+ic] (972 f4, 2 rounds)
    {
        float4 wr[2];
#pragma unroll
        for (int k = 0; k < 2; ++k) {
            const int v = tid + 512 * k;
            wr[k] = (v < 972) ? *(const float4*)(wbuf + (size_t)v * 4)
                              : make_float4(0.f, 0.f, 0.f, 0.f);
        }
#pragma unroll
        for (int k = 0; k < 2; ++k) {
            const int v = tid + 512 * k;
            if (v < 972) {
                const float e[4] = {wr[k].x, wr[k].y, wr[k].z, wr[k].w};
#pragma unroll
                for (int j = 0; j < 4; ++j) {
                    const int n  = v * 4 + j;
                    const int oc = n / 432;
                    const int r  = n - 432 * oc;
                    const int ic = r / 9;
                    const int kk = r - 9 * ic;
                    lwT[oc * 432 + kk * 48 + ic] = f2bf(e[j]);
                }
            }
        }
    }

    __syncthreads();   // B1: xs + lwT ready

    // ---- B-fragments: 14 x ds_read_b128
    short8 wf[14];
    {
        const unsigned short* lwb = lwT + l15 * 432 + kg * 8;
#pragma unroll
        for (int kb = 0; kb < 14; ++kb) {
            short8 w = {0, 0, 0, 0, 0, 0, 0, 0};
            if (l15 < 9 && !(kb == 13 && kg >= 2))
                w = *(const short8*)(lwb + kb * 32);
            wf[kb] = w;
        }
    }

    // ---- MFMA: 14 K-blocks x 2 row-tiles (wave's px cols 16*xh.., rows r0,r0+1)
    f32x4 acc0 = {0.f, 0.f, 0.f, 0.f}, acc1 = acc0;
#pragma unroll
    for (int kb = 0; kb < 14; ++kb) {
        const int k0 = kb * 32 + kg * 8;
        int off = 0;
        if (k0 < 432) {
            const int kk = k0 / 48, ic0 = k0 - 48 * kk;
            const int ky = kk / 3, kx = kk - 3 * ky;
            off = ((r0 + ky) * 34 + 16 * xh + l15 + kx) * 48 + ic0;   // 16B-aligned
        }
        short8 a0 = *(const short8*)(xs + off);
        short8 a1 = *(const short8*)(xs + off + 1632);                // +1 px row (34*48)
        acc0 = __builtin_amdgcn_mfma_f32_16x16x32_bf16(a0, wf[kb], acc0, 0, 0, 0);
        acc1 = __builtin_amdgcn_mfma_f32_16x16x32_bf16(a1, wf[kb], acc1, 0, 0, 0);
    }

    __syncthreads();   // B2: lwT reads done -> lf may overwrite

    // ---- apply-phase mapping: thread = (pq 0..7, py 0..7, clo 0..7)
    const int pq  = tid & 7;
    const int py  = (tid >> 3) & 7;
    const int clo = tid >> 6;                  // channel block: ch = clo*8 + it
    const int col0 = X0 + pq * 4;
    const bool gl = (col0 >= 4);               // left f4 (cols col0-4..-1) valid
    const bool gr = (col0 <= WSZ - 8);         // right f4 (cols col0+4..+7) valid

    bool rg[3]; int ro[3];
#pragma unroll
    for (int ky = 0; ky < 3; ++ky) {
        const int Y = Y0 + py - 1 + ky;
        rg[ky] = ((unsigned)Y < HSZ);
        ro[ky] = Y * WSZ + col0;
    }
    const float* hp = hbuf + ((size_t)b * NFC + clo * 8) * PLANE;

    // prefetch iter-0 h (in flight across lf-write + B3)
    float4 pf[9];
#pragma unroll
    for (int ky = 0; ky < 3; ++ky) {
        pf[ky * 3 + 0] = (rg[ky] && gl) ? *(const float4*)(hp + ro[ky] - 4)
                                        : make_float4(0.f, 0.f, 0.f, 0.f);
        pf[ky * 3 + 1] = rg[ky] ? *(const float4*)(hp + ro[ky])
                                : make_float4(0.f, 0.f, 0.f, 0.f);
        pf[ky * 3 + 2] = (rg[ky] && gr) ? *(const float4*)(hp + ro[ky] + 4)
                                        : make_float4(0.f, 0.f, 0.f, 0.f);
    }

    // ---- filters -> lf (relu + bias)
    if (l15 < 9) {
#pragma unroll
        for (int t = 0; t < 2; ++t) {
            const int pyw = r0 + t;
            const f32x4 A = t ? acc1 : acc0;
#pragma unroll
            for (int r = 0; r < 4; ++r)
                lf[l15 * 256 + pyw * 32 + 16 * xh + kg * 4 + r] = fmaxf(A[r] + bv, 0.f);
        }
    }

    __syncthreads();   // B3: lf ready

    // per-pixel filters into registers
    float4 flt[9];
#pragma unroll
    for (int oc = 0; oc < 9; ++oc)
        flt[oc] = *(const float4*)(lf + oc * 256 + py * 32 + pq * 4);

    float* op = out + ((size_t)b * NFC + clo * 8) * PLANE
                    + (size_t)(Y0 + py) * WSZ + col0;

    // ---- 8 channel iterations, direct-global vectorized reads, no barriers
#pragma unroll
    for (int it = 0; it < 8; ++it) {
        const float* p = hp + (size_t)it * PLANE;

        float a[4] = {0.f, 0.f, 0.f, 0.f};
#pragma unroll
        for (int ky = 0; ky < 3; ++ky) {
            float4 lv, mv, rv;
            if (it == 0) {
                lv = pf[ky * 3 + 0]; mv = pf[ky * 3 + 1]; rv = pf[ky * 3 + 2];
            } else {
                lv = (rg[ky] && gl) ? *(const float4*)(p + ro[ky] - 4)
                                    : make_float4(0.f, 0.f, 0.f, 0.f);
                mv = rg[ky] ? *(const float4*)(p + ro[ky])
                            : make_float4(0.f, 0.f, 0.f, 0.f);
                rv = (rg[ky] && gr) ? *(const float4*)(p + ro[ky] + 4)
                                    : make_float4(0.f, 0.f, 0.f, 0.f);
            }
            const float vs[12] = {lv.x, lv.y, lv.z, lv.w,
                                  mv.x, mv.y, mv.z, mv.w,
                                  rv.x, rv.y, rv.z, rv.w};
#pragma unroll
            for (int kx = 0; kx < 3; ++kx)
#pragma unroll
                for (int j = 0; j < 4; ++j)
                    a[j] = fmaf(vs[3 + kx + j], flt[ky * 3 + kx][j], a[j]);
        }

        *(float4*)(op + (size_t)it * PLANE)
            = make_float4(a[0], a[1], a[2], a[3]);
    }
}

extern "C" void kernel_launch(void* const* d_in, const int* in_sizes, int n_in,
                              void* d_out, int out_size, void* d_ws, size_t ws_size,
                              hipStream_t stream) {
    const float* h      = (const float*)d_in[0];
    const float* i_t    = (const float*)d_in[1];
    const float* conv_w = (const float*)d_in[2];
    const float* conv_b = (const float*)d_in[3];
    float* out = (float*)d_out;

    const int B = in_sizes[0] / (NFC * PLANE);
    dim3 grid(8, 32, B);
    fused_dynfilter_v6<<<grid, 512, 0, stream>>>(h, i_t, conv_w, conv_b, out);
}